// Round 4
// baseline (228.685 us; speedup 1.0000x reference)
//
#include <hip/hip_runtime.h>
#include <hip/hip_bf16.h>
#include <math.h>

#define BATCH 8
#define SEQ   2048
#define CH    256
#define NH    4
#define HD    64
#define NQB   (SEQ / 64)      // 32 query tiles of 64
// Q pre-scale: 64^-0.5 * log2(e)  (softmax runs in exp2 domain)
#define QSCALE 0.18033688011112042f

typedef short  bfrag __attribute__((ext_vector_type(8)));  // 8 bf16 (4 VGPRs)
typedef float  ffrag __attribute__((ext_vector_type(4)));  // 4 fp32 acc
typedef unsigned short ushort_t;

__device__ __forceinline__ unsigned short f2bf(float f) {
    union { float f; unsigned int u; } v; v.f = f;
    unsigned int r = v.u + 0x7FFF + ((v.u >> 16) & 1);   // RNE
    return (unsigned short)(r >> 16);
}
__device__ __forceinline__ unsigned int pack2(float a, float b) {
    const __hip_bfloat162 p = __float22bfloat162_rn(make_float2(a, b));
    return *(const unsigned int*)&p;
}

// ---------------------------------------------------------------------------
// Prep: x -> bf16 [M][C] (vectorized x8), Wqkv/Wproj -> transposed bf16.
// xb aliases attn_b in workspace (dead until attn writes, which is post-qkv).
// ---------------------------------------------------------------------------
#define WQN (CH * 3 * CH)            // 196608
#define WPN (CH * CH)                // 65536
#define XN  (BATCH * SEQ * CH)       // 4,194,304
#define XN8 (XN / 8)                 // 524,288

__global__ __launch_bounds__(256) void prep_kernel(
    const float* __restrict__ x,
    const float* __restrict__ Wqkv, const float* __restrict__ Wproj,
    ushort_t* __restrict__ xb,
    ushort_t* __restrict__ WqkvT, ushort_t* __restrict__ WprojT) {
    const int fid = blockIdx.x * 256 + threadIdx.x;
    if (fid < XN8) {
        const float4 a = *(const float4*)&x[(size_t)fid * 8];
        const float4 c = *(const float4*)&x[(size_t)fid * 8 + 4];
        uint4 pk;
        pk.x = pack2(a.x, a.y); pk.y = pack2(a.z, a.w);
        pk.z = pack2(c.x, c.y); pk.w = pack2(c.z, c.w);
        *(uint4*)&xb[(size_t)fid * 8] = pk;
    } else {
        const int id = fid - XN8;
        if (id < WQN) {
            const int n = id >> 8, k = id & 255;
            WqkvT[n * CH + k] = f2bf(Wqkv[k * (3 * CH) + n]);
        } else if (id < WQN + WPN) {
            const int i = id - WQN;
            const int n = i >> 8, k = i & 255;
            WprojT[n * CH + k] = f2bf(Wproj[k * CH + n]);
        }
    }
}

// ---------------------------------------------------------------------------
// QKV MFMA GEMM: xb bf16 @ WqkvT^T + bqkv -> bf16 Q(*QSCALE),K [BH,T,D],
// V^T [BH,D,T]. 128x128 tile, 4 waves each 64x64, BK=64.
// ---------------------------------------------------------------------------
#define GLS 72   // LDS row stride in ushorts (144 B, 16B-aligned)

__global__ __launch_bounds__(256) void qkv_mfma_kernel(
    const ushort_t* __restrict__ xb, const ushort_t* __restrict__ Wt,
    const float* __restrict__ bias,
    ushort_t* __restrict__ Qb, ushort_t* __restrict__ Kb,
    ushort_t* __restrict__ Vtb) {
    __shared__ ushort_t smem[2 * 128 * GLS];   // As | Bs; reused as T[128][136]
    ushort_t* As = smem;
    ushort_t* Bs = smem + 128 * GLS;

    const int tid = threadIdx.x;
    const int wv  = tid >> 6;
    const int ln  = tid & 63;
    const int l15 = ln & 15;
    const int l4  = ln >> 4;
    const int wr  = wv >> 1;          // wave row 0..1
    const int wc  = wv & 1;           // wave col 0..1
    const int n0  = blockIdx.x * 128;
    const int m0  = blockIdx.y * 128;

    ffrag acc[4][4];
    #pragma unroll
    for (int i = 0; i < 4; i++)
        #pragma unroll
        for (int j = 0; j < 4; j++) acc[i][j] = (ffrag){0.f, 0.f, 0.f, 0.f};

    for (int k0 = 0; k0 < CH; k0 += 64) {
        #pragma unroll
        for (int r = 0; r < 4; r++) {
            const int fid = tid + r * 256;
            const int row = fid >> 3, c8 = (fid & 7) * 8;
            *(uint4*)&As[row * GLS + c8] = *(const uint4*)&xb[(size_t)(m0 + row) * CH + k0 + c8];
            *(uint4*)&Bs[row * GLS + c8] = *(const uint4*)&Wt[(n0 + row) * CH + k0 + c8];
        }
        __syncthreads();
        #pragma unroll
        for (int kk = 0; kk < 64; kk += 32) {
            bfrag a[4], b[4];
            #pragma unroll
            for (int i = 0; i < 4; i++)
                a[i] = *(const bfrag*)&As[(wr * 64 + i * 16 + l15) * GLS + kk + l4 * 8];
            #pragma unroll
            for (int j = 0; j < 4; j++)
                b[j] = *(const bfrag*)&Bs[(wc * 64 + j * 16 + l15) * GLS + kk + l4 * 8];
            #pragma unroll
            for (int i = 0; i < 4; i++)
                #pragma unroll
                for (int j = 0; j < 4; j++)
                    acc[i][j] = __builtin_amdgcn_mfma_f32_16x16x32_bf16(a[i], b[j], acc[i][j], 0, 0, 0);
        }
        __syncthreads();
    }

    const int mat = n0 >> 8;                 // block-uniform: 0=Q 1=K 2=V
    const int b   = m0 >> 11;                // block-uniform
    const int t0  = m0 & (SEQ - 1);
    ushort_t (*T)[136] = (ushort_t(*)[136])smem;

    if (mat < 2) {
        // Q/K: transpose to T[t_local][n_local], then coalesced [T,D] stores.
        const float sc = (mat == 0) ? QSCALE : 1.0f;
        #pragma unroll
        for (int j = 0; j < 4; j++) {
            const int n_local = wc * 64 + j * 16 + l15;
            const float bj = bias[n0 + n_local];
            #pragma unroll
            for (int i = 0; i < 4; i++) {
                const int m_base = wr * 64 + i * 16 + l4 * 4;
                #pragma unroll
                for (int r = 0; r < 4; r++)
                    T[m_base + r][n_local] = f2bf((acc[i][j][r] + bj) * sc);
            }
        }
        __syncthreads();
        ushort_t* dst = (mat == 0) ? Qb : Kb;
        #pragma unroll
        for (int rr = 0; rr < 8; rr++) {
            const int fid = tid + rr * 256;
            const int row = fid >> 4;            // t_local 0..127
            const int c8  = (fid & 15) * 8;      // n_local chunk
            const int n_glob = n0 + c8;
            const int h = (n_glob >> 6) & 3;
            const int d = n_glob & 63;
            *(uint4*)&dst[((size_t)((b * NH + h) * SEQ) + t0 + row) * HD + d] =
                *(const uint4*)&T[row][c8];
        }
    } else {
        // V: transpose to T[n_local][m_local], then coalesced [D,T] stores.
        #pragma unroll
        for (int j = 0; j < 4; j++) {
            const int n_local = wc * 64 + j * 16 + l15;
            const float bj = bias[n0 + n_local];
            #pragma unroll
            for (int i = 0; i < 4; i++) {
                const int m_base = wr * 64 + i * 16 + l4 * 4;
                ushort4 pk;
                pk.x = f2bf(acc[i][j][0] + bj);
                pk.y = f2bf(acc[i][j][1] + bj);
                pk.z = f2bf(acc[i][j][2] + bj);
                pk.w = f2bf(acc[i][j][3] + bj);
                *(ushort4*)&T[n_local][m_base] = pk;
            }
        }
        __syncthreads();
        #pragma unroll
        for (int rr = 0; rr < 8; rr++) {
            const int fid = tid + rr * 256;
            const int row = fid >> 4;            // n_local 0..127
            const int c8  = (fid & 15) * 8;      // m_local chunk
            const int n_glob = n0 + row;
            const int h = (n_glob >> 6) & 3;
            const int d = n_glob & 63;
            *(uint4*)&Vtb[(size_t)((b * NH + h) * HD + d) * SEQ + t0 + c8] =
                *(const uint4*)&T[row][c8];
        }
    }
}

// ---------------------------------------------------------------------------
// MFMA flash attention (causal), S^T form, exp2 STATIC-MAX softmax,
// O^T = V^T * P^T — BARRIER-FREE version.
// Static-max softmax makes O and l pure sums over k-tiles -> no sequential
// dependency. K/V fragments are read DIRECT from global (fully-coalesced 16B
// chunks; the 4 waves of a block issue identical addresses so L1 serves the
// redundancy; same-bh blocks land on the same XCD since g%8==bh%8, so K/V is
// L2-resident). Only the wave-private P tile goes through LDS (double-
// buffered to break the loop-carried write->read dependency). ZERO
// __syncthreads in the kernel: 16 independent wave streams per CU.
// l-denominator cross-lane shuffles deferred to the epilogue (in-lane
// partials are disjoint over the l4 group - same additions, reordered).
// ---------------------------------------------------------------------------
__global__ __launch_bounds__(256, 4) void attn_mfma_kernel(
    const ushort_t* __restrict__ Qb, const ushort_t* __restrict__ Kb,
    const ushort_t* __restrict__ Vtb, ushort_t* __restrict__ out) {
    __shared__ ushort_t Ps[2][64 * 64];    // double-buffered P (8 KB each)

    const int tid = threadIdx.x;
    const int wv  = tid >> 6;
    const int ln  = tid & 63;
    const int l15 = ln & 15;
    const int l4  = ln >> 4;
    const int e   = l15 & 7;

    const int L  = blockIdx.x;
    const int g  = L & 255;
    const int s4 = L >> 8;               // dispatch wave 0..3
    const int v  = g >> 5;               // 0..7
    // longest-first; per-CU slot set {31-v, 16+v, 15-v, v} sums to 66 iters
    const int qb = (s4 == 0) ? (31 - v) : (s4 == 1) ? (16 + v) : (s4 == 2) ? (15 - v) : v;
    const int bh = g & 31;
    const int b  = bh >> 2;
    const int h  = bh & 3;

    // ---- Q fragments straight from global (B-operand: B[n=q][k]) ----
    const ushort_t* Qp = Qb + ((size_t)(bh * SEQ + qb * 64 + wv * 16 + l15)) * HD + l4 * 8;
    const bfrag bq0 = *(const bfrag*)Qp;
    const bfrag bq1 = *(const bfrag*)(Qp + 32);

    // ---- direct-global K/V fragment base addresses ----
    // K frag (A-op rows = k-index t): row l15 within 16-row band, chunk l4*8 of d
    const ushort_t* Kf = Kb  + (size_t)bh * SEQ * HD + l15 * HD + l4 * 8;
    // V^T frag (A-op rows = d): row l15 within 16-row band, chunk l4*8 of t
    const ushort_t* Vf = Vtb + (size_t)bh * HD * SEQ + l15 * SEQ + l4 * 8;

    // ---- P exchange offsets (wave-private 16-row band, swizzled) ----
    const int pf0 = (wv * 16 + l15) * 64 + ((l4 ^ e) * 8);
    const int pp  = e >> 1;
    const int pwb = (wv * 16 + l15) * 64 + (((l4 >> 1) ^ (e & 1)) * 8) + (l4 & 1) * 4;

    ffrag o[4];   // O^T accumulator: o[n][r] = O^T[d = n*16+l4*4+r][q = l15]
    #pragma unroll
    for (int n = 0; n < 4; n++) o[n] = (ffrag){0.f, 0.f, 0.f, 0.f};
    float l_q = 0.f;                      // in-lane partial; shuffles at end
    const int qg_l = qb * 64 + wv * 16 + l15;

    for (int kt = 0; kt <= qb; kt++) {
        const ushort_t* Kt = Kf + (size_t)kt * 64 * HD;
        const ushort_t* Vt = Vf + kt * 64;

        // ---- V fragments issued FIRST (no deps -> in flight during QK/SM) --
        bfrag av0[4], av1[4];
        #pragma unroll
        for (int n = 0; n < 4; n++) {
            av0[n] = *(const bfrag*)&Vt[n * 16 * SEQ];
            av1[n] = *(const bfrag*)&Vt[n * 16 * SEQ + 32];
        }

        // ---- S^T = K Q^T : s[n][r] = S[q=l15][k = n*16 + l4*4 + r] ----
        ffrag s[4];
        #pragma unroll
        for (int n = 0; n < 4; n++) {
            const bfrag ak0 = *(const bfrag*)&Kt[n * 16 * HD];
            const bfrag ak1 = *(const bfrag*)&Kt[n * 16 * HD + 32];
            ffrag z = (ffrag){0.f, 0.f, 0.f, 0.f};
            z = __builtin_amdgcn_mfma_f32_16x16x32_bf16(ak0, bq0, z, 0, 0, 0);
            z = __builtin_amdgcn_mfma_f32_16x16x32_bf16(ak1, bq1, z, 0, 0, 0);
            s[n] = z;
        }
        if (kt == qb) {   // causal mask on the diagonal tile
            #pragma unroll
            for (int n = 0; n < 4; n++)
                #pragma unroll
                for (int r = 0; r < 4; r++)
                    if (kt * 64 + n * 16 + l4 * 4 + r > qg_l) s[n][r] = -INFINITY;
        }

        // ---- softmax (exp2 domain, static max): p = exp2(S'); exp2(-inf)=0 --
        #pragma unroll
        for (int n = 0; n < 4; n++)
            #pragma unroll
            for (int r = 0; r < 4; r++) {
                const float p = __builtin_amdgcn_exp2f(s[n][r]);
                s[n][r] = p;
                l_q += p;
            }

        // ---- pack P (bf16, A/B-layout rows q, swizzled, wave-private) ----
        ushort_t* Pb = Ps[kt & 1];
        #pragma unroll
        for (int n = 0; n < 4; n++) {
            uint2 pk;
            pk.x = pack2(s[n][0], s[n][1]);
            pk.y = pack2(s[n][2], s[n][3]);
            *(uint2*)&Pb[pwb + ((n ^ pp) << 4)] = pk;
        }

        // ---- O^T += V^T @ P^T ----
        const bfrag ap0 = *(const bfrag*)&Pb[pf0];
        const bfrag ap1 = *(const bfrag*)&Pb[pf0 ^ 32];
        #pragma unroll
        for (int n = 0; n < 4; n++) {
            o[n] = __builtin_amdgcn_mfma_f32_16x16x32_bf16(av0[n], ap0, o[n], 0, 0, 0);
            o[n] = __builtin_amdgcn_mfma_f32_16x16x32_bf16(av1[n], ap1, o[n], 0, 0, 0);
        }
    }

    // ---- deferred l reduction: l4-group partials are disjoint k-subsets ----
    l_q += __shfl_xor(l_q, 16);
    l_q += __shfl_xor(l_q, 32);

    // ---- normalize + store O (bf16, [B,T,C]): in-lane 1/l, vector stores ----
    const float li = 1.0f / l_q;
    const int tq = qb * 64 + wv * 16 + l15;        // this lane's q row
    ushort_t* op = out + (size_t)(b * SEQ + tq) * CH + h * HD;
    #pragma unroll
    for (int n = 0; n < 4; n++) {
        ushort4 pk;
        pk.x = f2bf(o[n][0] * li);
        pk.y = f2bf(o[n][1] * li);
        pk.z = f2bf(o[n][2] * li);
        pk.w = f2bf(o[n][3] * li);
        *(ushort4*)&op[n * 16 + l4 * 4] = pk;      // d = n*16 + l4*4 .. +3
    }
}

// ---------------------------------------------------------------------------
// Proj MFMA GEMM: attn_b @ WprojT^T + bproj -> fp32 out.
// 128x64 tile (4 waves: 2x2, each 64x32), grid 512 -> 2 blocks/CU.
// ---------------------------------------------------------------------------
__global__ __launch_bounds__(256) void proj_mfma_kernel(
    const ushort_t* __restrict__ Ab, const ushort_t* __restrict__ Wt,
    const float* __restrict__ bias, float* __restrict__ O) {
    __shared__ ushort_t smem[(128 + 64) * GLS];
    ushort_t* As = smem;
    ushort_t* Bs = smem + 128 * GLS;

    const int tid = threadIdx.x;
    const int wv  = tid >> 6;
    const int ln  = tid & 63;
    const int l15 = ln & 15;
    const int l4  = ln >> 4;
    const int wr  = wv >> 1;          // 0..1 -> 64-row band
    const int wc  = wv & 1;           // 0..1 -> 32-col band
    const int n0  = blockIdx.x * 64;
    const int m0  = blockIdx.y * 128;

    ffrag acc[4][2];
    #pragma unroll
    for (int i = 0; i < 4; i++)
        #pragma unroll
        for (int j = 0; j < 2; j++) acc[i][j] = (ffrag){0.f, 0.f, 0.f, 0.f};

    for (int k0 = 0; k0 < CH; k0 += 64) {
        #pragma unroll
        for (int r = 0; r < 4; r++) {   // A: 128x64 = 1024 chunks
            const int fid = tid + r * 256;
            const int row = fid >> 3, c8 = (fid & 7) * 8;
            *(uint4*)&As[row * GLS + c8] = *(const uint4*)&Ab[(size_t)(m0 + row) * CH + k0 + c8];
        }
        #pragma unroll
        for (int r = 0; r < 2; r++) {   // B: 64x64 = 512 chunks
            const int fid = tid + r * 256;
            const int row = fid >> 3, c8 = (fid & 7) * 8;
            *(uint4*)&Bs[row * GLS + c8] = *(const uint4*)&Wt[(n0 + row) * CH + k0 + c8];
        }
        __syncthreads();
        #pragma unroll
        for (int kk = 0; kk < 64; kk += 32) {
            bfrag a[4], b[2];
            #pragma unroll
            for (int i = 0; i < 4; i++)
                a[i] = *(const bfrag*)&As[(wr * 64 + i * 16 + l15) * GLS + kk + l4 * 8];
            #pragma unroll
            for (int j = 0; j < 2; j++)
                b[j] = *(const bfrag*)&Bs[(wc * 32 + j * 16 + l15) * GLS + kk + l4 * 8];
            #pragma unroll
            for (int i = 0; i < 4; i++)
                #pragma unroll
                for (int j = 0; j < 2; j++)
                    acc[i][j] = __builtin_amdgcn_mfma_f32_16x16x32_bf16(a[i], b[j], acc[i][j], 0, 0, 0);
        }
        __syncthreads();
    }

    #pragma unroll
    for (int j = 0; j < 2; j++) {
        const int n = n0 + wc * 32 + j * 16 + l15;
        const float bj = bias[n];
        #pragma unroll
        for (int i = 0; i < 4; i++) {
            const int m = m0 + wr * 64 + i * 16 + l4 * 4;
            #pragma unroll
            for (int r = 0; r < 4; r++)
                O[(size_t)(m + r) * CH + n] = acc[i][j][r] + bj;
        }
    }
}

extern "C" void kernel_launch(void* const* d_in, const int* in_sizes, int n_in,
                              void* d_out, int out_size, void* d_ws, size_t ws_size,
                              hipStream_t stream) {
    const float* x     = (const float*)d_in[0];
    const float* Wqkv  = (const float*)d_in[1];
    const float* bqkv  = (const float*)d_in[2];
    const float* Wproj = (const float*)d_in[3];
    const float* bproj = (const float*)d_in[4];
    float* out = (float*)d_out;

    const size_t BHTD = (size_t)BATCH * NH * SEQ * HD;   // 4,194,304
    ushort_t* WqkvT  = (ushort_t*)d_ws;
    ushort_t* WprojT = WqkvT + (size_t)3 * CH * CH;
    ushort_t* Qb     = WprojT + (size_t)CH * CH;
    ushort_t* Kb     = Qb + BHTD;
    ushort_t* Vtb    = Kb + BHTD;
    ushort_t* attn_b = Vtb + BHTD;
    ushort_t* xb     = attn_b;          // alias: xb dead before attn writes

    const int M = BATCH * SEQ;   // 16384

    {
        const int total = XN8 + WQN + WPN;          // 786,432
        prep_kernel<<<(total + 255) / 256, 256, 0, stream>>>(x, Wqkv, Wproj, xb, WqkvT, WprojT);
    }
    {
        dim3 grid((3 * CH) / 128, M / 128);
        qkv_mfma_kernel<<<grid, 256, 0, stream>>>(xb, WqkvT, bqkv, Qb, Kb, Vtb);
    }
    {
        attn_mfma_kernel<<<dim3(NQB * BATCH * NH), 256, 0, stream>>>(Qb, Kb, Vtb, attn_b);
    }
    {
        dim3 grid(CH / 64, M / 128);
        proj_mfma_kernel<<<grid, 256, 0, stream>>>(attn_b, WprojT, bproj, out);
    }
}

// Round 7
// 133.525 us; speedup vs baseline: 1.7127x; 1.7127x over previous
//
#include <hip/hip_runtime.h>
#include <hip/hip_bf16.h>
#include <math.h>

#define BATCH 8
#define SEQ   2048
#define CH    256
#define NH    4
#define HD    64
#define NQB   (SEQ / 64)      // 32 query tiles of 64
// Q pre-scale: 64^-0.5 * log2(e)  (softmax runs in exp2 domain)
#define QSCALE 0.18033688011112042f

typedef short  bfrag __attribute__((ext_vector_type(8)));  // 8 bf16 (4 VGPRs)
typedef float  ffrag __attribute__((ext_vector_type(4)));  // 4 fp32 acc
typedef unsigned short ushort_t;
typedef unsigned int u32;

__device__ __forceinline__ unsigned short f2bf(float f) {
    union { float f; unsigned int u; } v; v.f = f;
    unsigned int r = v.u + 0x7FFF + ((v.u >> 16) & 1);   // RNE
    return (unsigned short)(r >> 16);
}
__device__ __forceinline__ unsigned int pack2(float a, float b) {
    const __hip_bfloat162 p = __float22bfloat162_rn(make_float2(a, b));
    return *(const unsigned int*)&p;
}
// async global->LDS, 16B/lane. LDS base must be wave-uniform; global per-lane.
__device__ __forceinline__ void gload16(const ushort_t* g, ushort_t* l) {
    __builtin_amdgcn_global_load_lds(
        (const __attribute__((address_space(1))) u32*)g,
        (__attribute__((address_space(3))) u32*)l, 16, 0, 0);
}

// ---------------------------------------------------------------------------
// Prep: x -> bf16 [M][C] (vectorized x8), Wqkv/Wproj -> transposed bf16.
// xb aliases attn_b in workspace (dead until attn writes, which is post-qkv).
// ---------------------------------------------------------------------------
#define WQN (CH * 3 * CH)            // 196608
#define WPN (CH * CH)                // 65536
#define XN  (BATCH * SEQ * CH)       // 4,194,304
#define XN8 (XN / 8)                 // 524,288

__global__ __launch_bounds__(256) void prep_kernel(
    const float* __restrict__ x,
    const float* __restrict__ Wqkv, const float* __restrict__ Wproj,
    ushort_t* __restrict__ xb,
    ushort_t* __restrict__ WqkvT, ushort_t* __restrict__ WprojT) {
    const int fid = blockIdx.x * 256 + threadIdx.x;
    if (fid < XN8) {
        const float4 a = *(const float4*)&x[(size_t)fid * 8];
        const float4 c = *(const float4*)&x[(size_t)fid * 8 + 4];
        uint4 pk;
        pk.x = pack2(a.x, a.y); pk.y = pack2(a.z, a.w);
        pk.z = pack2(c.x, c.y); pk.w = pack2(c.z, c.w);
        *(uint4*)&xb[(size_t)fid * 8] = pk;
    } else {
        const int id = fid - XN8;
        if (id < WQN) {
            const int n = id >> 8, k = id & 255;
            WqkvT[n * CH + k] = f2bf(Wqkv[k * (3 * CH) + n]);
        } else if (id < WQN + WPN) {
            const int i = id - WQN;
            const int n = i >> 8, k = i & 255;
            WprojT[n * CH + k] = f2bf(Wproj[k * CH + n]);
        }
    }
}

// ---------------------------------------------------------------------------
// QKV MFMA GEMM: xb bf16 @ WqkvT^T + bqkv -> bf16 Q(*QSCALE),K [BH,T,D],
// V^T [BH,D,T]. 128x128 tile, 4 waves each 64x64, BK=64.
// Staging via global_load_lds width=16 (async, no VGPR round-trip).
// LDS layout is LINEAR [128][64]; bank-conflict-free reads via XOR swizzle
// applied on BOTH sides: per-lane global source pre-swizzle (chunk ^= row&7)
// + same XOR on the fragment-read chunk index (rule: both-sides-or-neither).
// ---------------------------------------------------------------------------
#define GLS 72   // LDS row stride in ushorts (proj kernel only)

__global__ __launch_bounds__(256) void qkv_mfma_kernel(
    const ushort_t* __restrict__ xb, const ushort_t* __restrict__ Wt,
    const float* __restrict__ bias,
    ushort_t* __restrict__ Qb, ushort_t* __restrict__ Kb,
    ushort_t* __restrict__ Vtb) {
    __shared__ ushort_t smem[128 * 136];   // As[0,8K) Bs[8K,16K) ; epilogue T[128][136]
    ushort_t* As = smem;
    ushort_t* Bs = smem + 128 * 64;

    const int tid = threadIdx.x;
    const int wv  = tid >> 6;
    const int ln  = tid & 63;
    const int l15 = ln & 15;
    const int l4  = ln >> 4;
    const int e   = l15 & 7;
    const int wr  = wv >> 1;          // wave row 0..1
    const int wc  = wv & 1;           // wave col 0..1
    const int n0  = blockIdx.x * 128;
    const int m0  = blockIdx.y * 128;

    // staging geometry: each wave moves 4x1KB chunks per matrix per K-step.
    const int grow = ln >> 3;                         // row within 8-row chunk
    const int swz  = ((ln & 7) ^ grow) * 8;           // pre-swizzled src chunk

    ffrag acc[4][4];
    #pragma unroll
    for (int i = 0; i < 4; i++)
        #pragma unroll
        for (int j = 0; j < 4; j++) acc[i][j] = (ffrag){0.f, 0.f, 0.f, 0.f};

    for (int k0 = 0; k0 < CH; k0 += 64) {
        #pragma unroll
        for (int i = 0; i < 4; i++) {
            const int rowA = (i * 4 + wv) * 8 + grow;       // 0..127
            gload16(&xb[(size_t)(m0 + rowA) * CH + k0 + swz], &As[(i * 4 + wv) * 512]);
            gload16(&Wt[(size_t)(n0 + rowA) * CH + k0 + swz], &Bs[(i * 4 + wv) * 512]);
        }
        __syncthreads();   // drains vmcnt (incl. global_load_lds) at barrier
        #pragma unroll
        for (int kk = 0; kk < 64; kk += 32) {
            bfrag a[4], b[4];
            #pragma unroll
            for (int i = 0; i < 4; i++) {
                const int R = wr * 64 + i * 16 + l15;       // R&7 == e
                a[i] = *(const bfrag*)&As[R * 64 + ((((kk >> 3) + l4) ^ e) * 8)];
            }
            #pragma unroll
            for (int j = 0; j < 4; j++) {
                const int R = wc * 64 + j * 16 + l15;       // R&7 == e
                b[j] = *(const bfrag*)&Bs[R * 64 + ((((kk >> 3) + l4) ^ e) * 8)];
            }
            #pragma unroll
            for (int i = 0; i < 4; i++)
                #pragma unroll
                for (int j = 0; j < 4; j++)
                    acc[i][j] = __builtin_amdgcn_mfma_f32_16x16x32_bf16(a[i], b[j], acc[i][j], 0, 0, 0);
        }
        __syncthreads();
    }

    const int mat = n0 >> 8;                 // block-uniform: 0=Q 1=K 2=V
    const int b   = m0 >> 11;                // block-uniform
    const int t0  = m0 & (SEQ - 1);
    ushort_t (*T)[136] = (ushort_t(*)[136])smem;

    if (mat < 2) {
        // Q/K: transpose to T[t_local][n_local], then coalesced [T,D] stores.
        const float sc = (mat == 0) ? QSCALE : 1.0f;
        #pragma unroll
        for (int j = 0; j < 4; j++) {
            const int n_local = wc * 64 + j * 16 + l15;
            const float bj = bias[n0 + n_local];
            #pragma unroll
            for (int i = 0; i < 4; i++) {
                const int m_base = wr * 64 + i * 16 + l4 * 4;
                #pragma unroll
                for (int r = 0; r < 4; r++)
                    T[m_base + r][n_local] = f2bf((acc[i][j][r] + bj) * sc);
            }
        }
        __syncthreads();
        ushort_t* dst = (mat == 0) ? Qb : Kb;
        #pragma unroll
        for (int rr = 0; rr < 8; rr++) {
            const int fid = tid + rr * 256;
            const int row = fid >> 4;            // t_local 0..127
            const int c8  = (fid & 15) * 8;      // n_local chunk
            const int n_glob = n0 + c8;
            const int h = (n_glob >> 6) & 3;
            const int d = n_glob & 63;
            *(uint4*)&dst[((size_t)((b * NH + h) * SEQ) + t0 + row) * HD + d] =
                *(const uint4*)&T[row][c8];
        }
    } else {
        // V: transpose to T[n_local][m_local], then coalesced [D,T] stores.
        #pragma unroll
        for (int j = 0; j < 4; j++) {
            const int n_local = wc * 64 + j * 16 + l15;
            const float bj = bias[n0 + n_local];
            #pragma unroll
            for (int i = 0; i < 4; i++) {
                const int m_base = wr * 64 + i * 16 + l4 * 4;
                ushort4 pk;
                pk.x = f2bf(acc[i][j][0] + bj);
                pk.y = f2bf(acc[i][j][1] + bj);
                pk.z = f2bf(acc[i][j][2] + bj);
                pk.w = f2bf(acc[i][j][3] + bj);
                *(ushort4*)&T[n_local][m_base] = pk;
            }
        }
        __syncthreads();
        #pragma unroll
        for (int rr = 0; rr < 8; rr++) {
            const int fid = tid + rr * 256;
            const int row = fid >> 4;            // n_local 0..127
            const int c8  = (fid & 15) * 8;      // m_local chunk
            const int n_glob = n0 + row;
            const int h = (n_glob >> 6) & 3;
            const int d = n_glob & 63;
            *(uint4*)&Vtb[(size_t)((b * NH + h) * HD + d) * SEQ + t0 + c8] =
                *(const uint4*)&T[row][c8];
        }
    }
}

// ---------------------------------------------------------------------------
// MFMA flash attention (causal), S^T form, exp2 STATIC-MAX softmax,
// O^T = V^T * P^T — R2 structure (LDS-staged K/V, double-buffered, ONE
// barrier per tile; best measured) + deferred-l reduction + s_setprio(1)
// around the MFMA clusters (T5: scheduler favors MFMA-phase waves; blocks on
// a CU are at independent k-tiles so there is real diversity to arbitrate).
// ---------------------------------------------------------------------------
__global__ __launch_bounds__(256, 4) void attn_mfma_kernel(
    const ushort_t* __restrict__ Qb, const ushort_t* __restrict__ Kb,
    const ushort_t* __restrict__ Vtb, ushort_t* __restrict__ out) {
    __shared__ ushort_t Ps[64 * 64];       // P tiles (wave-private 16-row bands)
    __shared__ ushort_t KV[4 * 64 * 64];   // K0 | K1 | V0 | V1 (8 KB each)

    const int tid = threadIdx.x;
    const int wv  = tid >> 6;
    const int ln  = tid & 63;
    const int l15 = ln & 15;
    const int l4  = ln >> 4;
    const int e   = l15 & 7;

    const int L  = blockIdx.x;
    const int g  = L & 255;
    const int s4 = L >> 8;               // dispatch wave 0..3
    const int v  = g >> 5;               // 0..7
    // longest-first; per-CU slot set {31-v, 16+v, 15-v, v} sums to 66 iters
    const int qb = (s4 == 0) ? (31 - v) : (s4 == 1) ? (16 + v) : (s4 == 2) ? (15 - v) : v;
    const int bh = g & 31;
    const int b  = bh >> 2;
    const int h  = bh & 3;

    // ---- Q fragments straight from global (B-operand: B[n=q][k]) ----
    const ushort_t* Qp = Qb + ((size_t)(bh * SEQ + qb * 64 + wv * 16 + l15)) * HD + l4 * 8;
    const bfrag bq0 = *(const bfrag*)Qp;
    const bfrag bq1 = *(const bfrag*)(Qp + 32);

    // ---- staging geometry ----
    const ushort_t* Kbase = Kb  + (size_t)bh * SEQ * HD;
    const ushort_t* Vbase = Vtb + (size_t)bh * HD * SEQ;
    const int srow  = tid >> 3;            // 0..31
    const int sc    = tid & 7;             // logical 16B-chunk
    const int goffA = srow * 64 + sc * 8;              // K global (ushorts)
    const int voffA = srow * SEQ + sc * 8;             // V global
    const int soffA = srow * 64 + ((sc ^ (srow & 7)) * 8);   // swizzled LDS

    // ---- fragment read offsets (precomputed, swizzled) ----
    const int kf0 = l15 * 64 + ((l4 ^ e) * 8);   // + n*1024 ; ^32 for k-chunk 1
    const int pf0 = (wv * 16 + l15) * 64 + ((l4 ^ e) * 8);
    const int pp  = e >> 1;
    const int pwb = (wv * 16 + l15) * 64 + (((l4 >> 1) ^ (e & 1)) * 8) + (l4 & 1) * 4;

    // ---- prologue: tile 0 -> regs -> LDS buf0 ; tile 1 -> regs ----
    uint4 kK0, kK1, kV0, kV1;
    kK0 = *(const uint4*)&Kbase[goffA];
    kK1 = *(const uint4*)&Kbase[goffA + 32 * 64];
    kV0 = *(const uint4*)&Vbase[voffA];
    kV1 = *(const uint4*)&Vbase[voffA + 32 * SEQ];
    *(uint4*)&KV[soffA]          = kK0;
    *(uint4*)&KV[soffA + 2048]   = kK1;
    *(uint4*)&KV[8192 + soffA]        = kV0;
    *(uint4*)&KV[8192 + soffA + 2048] = kV1;
    if (qb >= 1) {
        kK0 = *(const uint4*)&Kbase[4096 + goffA];
        kK1 = *(const uint4*)&Kbase[4096 + goffA + 32 * 64];
        kV0 = *(const uint4*)&Vbase[64 + voffA];
        kV1 = *(const uint4*)&Vbase[64 + voffA + 32 * SEQ];
    }

    ffrag o[4];   // O^T accumulator: o[n][r] = O^T[d = n*16+l4*4+r][q = l15]
    #pragma unroll
    for (int n = 0; n < 4; n++) o[n] = (ffrag){0.f, 0.f, 0.f, 0.f};
    float l_q = 0.f;                      // in-lane partial; shuffles at end
    const int qg_l = qb * 64 + wv * 16 + l15;

    for (int kt = 0; kt <= qb; kt++) {
        if (kt > 0) {
            // commit prefetched tile kt into buffer kt&1
            const int kb = (kt & 1) * 4096;
            *(uint4*)&KV[kb + soffA]          = kK0;
            *(uint4*)&KV[kb + soffA + 2048]   = kK1;
            *(uint4*)&KV[8192 + kb + soffA]        = kV0;
            *(uint4*)&KV[8192 + kb + soffA + 2048] = kV1;
            if (kt < qb) {   // issue loads for tile kt+1 (land during compute)
                const ushort_t* Kp  = Kbase + (kt + 1) * 4096;
                const ushort_t* Vtp = Vbase + (kt + 1) * 64;
                kK0 = *(const uint4*)&Kp[goffA];
                kK1 = *(const uint4*)&Kp[goffA + 32 * 64];
                kV0 = *(const uint4*)&Vtp[voffA];
                kV1 = *(const uint4*)&Vtp[voffA + 32 * SEQ];
            }
        }
        __syncthreads();   // the ONLY barrier in the iteration

        const ushort_t* Kbuf = KV + (kt & 1) * 4096;
        const ushort_t* Vbuf = KV + 8192 + (kt & 1) * 4096;

        // ---- S^T = K Q^T : s[n][r] = S[q=l15][k = n*16 + l4*4 + r] ----
        ffrag s[4];
        __builtin_amdgcn_s_setprio(1);
        #pragma unroll
        for (int n = 0; n < 4; n++) {
            const bfrag ak0 = *(const bfrag*)&Kbuf[n * 1024 + kf0];
            const bfrag ak1 = *(const bfrag*)&Kbuf[n * 1024 + (kf0 ^ 32)];
            ffrag z = (ffrag){0.f, 0.f, 0.f, 0.f};
            z = __builtin_amdgcn_mfma_f32_16x16x32_bf16(ak0, bq0, z, 0, 0, 0);
            z = __builtin_amdgcn_mfma_f32_16x16x32_bf16(ak1, bq1, z, 0, 0, 0);
            s[n] = z;
        }
        __builtin_amdgcn_s_setprio(0);
        if (kt == qb) {   // causal mask on the diagonal tile
            #pragma unroll
            for (int n = 0; n < 4; n++)
                #pragma unroll
                for (int r = 0; r < 4; r++)
                    if (kt * 64 + n * 16 + l4 * 4 + r > qg_l) s[n][r] = -INFINITY;
        }

        // ---- softmax (exp2 domain, static max): p = exp2(S'); exp2(-inf)=0 --
        #pragma unroll
        for (int n = 0; n < 4; n++)
            #pragma unroll
            for (int r = 0; r < 4; r++) {
                const float p = __builtin_amdgcn_exp2f(s[n][r]);
                s[n][r] = p;
                l_q += p;
            }

        // ---- pack P (bf16, A/B-layout rows q, swizzled, wave-private) ----
        #pragma unroll
        for (int n = 0; n < 4; n++) {
            uint2 pk;
            pk.x = pack2(s[n][0], s[n][1]);
            pk.y = pack2(s[n][2], s[n][3]);
            *(uint2*)&Ps[pwb + ((n ^ pp) << 4)] = pk;
        }

        // ---- O^T += V^T @ P^T ----
        const bfrag ap0 = *(const bfrag*)&Ps[pf0];
        const bfrag ap1 = *(const bfrag*)&Ps[pf0 ^ 32];
        __builtin_amdgcn_s_setprio(1);
        #pragma unroll
        for (int n = 0; n < 4; n++) {
            const bfrag av0 = *(const bfrag*)&Vbuf[n * 1024 + kf0];
            const bfrag av1 = *(const bfrag*)&Vbuf[n * 1024 + (kf0 ^ 32)];
            o[n] = __builtin_amdgcn_mfma_f32_16x16x32_bf16(av0, ap0, o[n], 0, 0, 0);
            o[n] = __builtin_amdgcn_mfma_f32_16x16x32_bf16(av1, ap1, o[n], 0, 0, 0);
        }
        __builtin_amdgcn_s_setprio(0);
    }

    // ---- deferred l reduction: l4-group partials are disjoint k-subsets ----
    l_q += __shfl_xor(l_q, 16);
    l_q += __shfl_xor(l_q, 32);

    // ---- normalize + store O (bf16, [B,T,C]): in-lane 1/l, vector stores ----
    const float li = 1.0f / l_q;
    const int tq = qb * 64 + wv * 16 + l15;        // this lane's q row
    ushort_t* op = out + (size_t)(b * SEQ + tq) * CH + h * HD;
    #pragma unroll
    for (int n = 0; n < 4; n++) {
        ushort4 pk;
        pk.x = f2bf(o[n][0] * li);
        pk.y = f2bf(o[n][1] * li);
        pk.z = f2bf(o[n][2] * li);
        pk.w = f2bf(o[n][3] * li);
        *(ushort4*)&op[n * 16 + l4 * 4] = pk;      // d = n*16 + l4*4 .. +3
    }
}

// ---------------------------------------------------------------------------
// Proj MFMA GEMM: attn_b @ WprojT^T + bproj -> fp32 out.
// 128x64 tile (4 waves: 2x2, each 64x32), grid 512 -> 2 blocks/CU.
// ---------------------------------------------------------------------------
__global__ __launch_bounds__(256) void proj_mfma_kernel(
    const ushort_t* __restrict__ Ab, const ushort_t* __restrict__ Wt,
    const float* __restrict__ bias, float* __restrict__ O) {
    __shared__ ushort_t smem[(128 + 64) * GLS];
    ushort_t* As = smem;
    ushort_t* Bs = smem + 128 * GLS;

    const int tid = threadIdx.x;
    const int wv  = tid >> 6;
    const int ln  = tid & 63;
    const int l15 = ln & 15;
    const int l4  = ln >> 4;
    const int wr  = wv >> 1;          // 0..1 -> 64-row band
    const int wc  = wv & 1;           // 0..1 -> 32-col band
    const int n0  = blockIdx.x * 64;
    const int m0  = blockIdx.y * 128;

    ffrag acc[4][2];
    #pragma unroll
    for (int i = 0; i < 4; i++)
        #pragma unroll
        for (int j = 0; j < 2; j++) acc[i][j] = (ffrag){0.f, 0.f, 0.f, 0.f};

    for (int k0 = 0; k0 < CH; k0 += 64) {
        #pragma unroll
        for (int r = 0; r < 4; r++) {   // A: 128x64 = 1024 chunks
            const int fid = tid + r * 256;
            const int row = fid >> 3, c8 = (fid & 7) * 8;
            *(uint4*)&As[row * GLS + c8] = *(const uint4*)&Ab[(size_t)(m0 + row) * CH + k0 + c8];
        }
        #pragma unroll
        for (int r = 0; r < 2; r++) {   // B: 64x64 = 512 chunks
            const int fid = tid + r * 256;
            const int row = fid >> 3, c8 = (fid & 7) * 8;
            *(uint4*)&Bs[row * GLS + c8] = *(const uint4*)&Wt[(n0 + row) * CH + k0 + c8];
        }
        __syncthreads();
        #pragma unroll
        for (int kk = 0; kk < 64; kk += 32) {
            bfrag a[4], b[2];
            #pragma unroll
            for (int i = 0; i < 4; i++)
                a[i] = *(const bfrag*)&As[(wr * 64 + i * 16 + l15) * GLS + kk + l4 * 8];
            #pragma unroll
            for (int j = 0; j < 2; j++)
                b[j] = *(const bfrag*)&Bs[(wc * 32 + j * 16 + l15) * GLS + kk + l4 * 8];
            #pragma unroll
            for (int i = 0; i < 4; i++)
                #pragma unroll
                for (int j = 0; j < 2; j++)
                    acc[i][j] = __builtin_amdgcn_mfma_f32_16x16x32_bf16(a[i], b[j], acc[i][j], 0, 0, 0);
        }
        __syncthreads();
    }

    #pragma unroll
    for (int j = 0; j < 2; j++) {
        const int n = n0 + wc * 32 + j * 16 + l15;
        const float bj = bias[n];
        #pragma unroll
        for (int i = 0; i < 4; i++) {
            const int m = m0 + wr * 64 + i * 16 + l4 * 4;
            #pragma unroll
            for (int r = 0; r < 4; r++)
                O[(size_t)(m + r) * CH + n] = acc[i][j][r] + bj;
        }
    }
}

extern "C" void kernel_launch(void* const* d_in, const int* in_sizes, int n_in,
                              void* d_out, int out_size, void* d_ws, size_t ws_size,
                              hipStream_t stream) {
    const float* x     = (const float*)d_in[0];
    const float* Wqkv  = (const float*)d_in[1];
    const float* bqkv  = (const float*)d_in[2];
    const float* Wproj = (const float*)d_in[3];
    const float* bproj = (const float*)d_in[4];
    float* out = (float*)d_out;

    const size_t BHTD = (size_t)BATCH * NH * SEQ * HD;   // 4,194,304
    ushort_t* WqkvT  = (ushort_t*)d_ws;
    ushort_t* WprojT = WqkvT + (size_t)3 * CH * CH;
    ushort_t* Qb     = WprojT + (size_t)CH * CH;
    ushort_t* Kb     = Qb + BHTD;
    ushort_t* Vtb    = Kb + BHTD;
    ushort_t* attn_b = Vtb + BHTD;
    ushort_t* xb     = attn_b;          // alias: xb dead before attn writes

    const int M = BATCH * SEQ;   // 16384

    {
        const int total = XN8 + WQN + WPN;          // 786,432
        prep_kernel<<<(total + 255) / 256, 256, 0, stream>>>(x, Wqkv, Wproj, xb, WqkvT, WprojT);
    }
    {
        dim3 grid((3 * CH) / 128, M / 128);
        qkv_mfma_kernel<<<grid, 256, 0, stream>>>(xb, WqkvT, bqkv, Qb, Kb, Vtb);
    }
    {
        attn_mfma_kernel<<<dim3(NQB * BATCH * NH), 256, 0, stream>>>(Qb, Kb, Vtb, attn_b);
    }
    {
        dim3 grid(CH / 64, M / 128);
        proj_mfma_kernel<<<grid, 256, 0, stream>>>(attn_b, WprojT, bproj, out);
    }
}